// Round 1
// baseline (186345.251 us; speedup 1.0000x reference)
//
#include <hip/hip_runtime.h>

// ---------------------------------------------------------------------------
// KAN-RNN on MI355X.
// Persistent kernel: 256 WGs = 32 row-groups (32 batch rows) x 8 col-slices
// (64 cols). Group = 8 WGs (one per XCD; slice = bid&7 so each XCD's L2 holds
// only its 1.2 MB weight slice for all 1024 steps). Per step: 2 layers, each
// = feature expansion (silu + 8 cubic B-spline bases per scalar, fp16) into
// XOR-swizzled LDS chunks + MFMA f32_16x16x32_f16 against fragment-linear
// pre-packed fp16 weights. h state carried in f32 through the recurrence.
// Group-local barriers via device-scope atomics (2/step).
// Workspace: W1p 4.85MB | W2p 4.72MB | h f32 2MB | h1 f32 2MB | counters.
// ---------------------------------------------------------------------------

typedef _Float16 f16;
typedef _Float16 f16x8 __attribute__((ext_vector_type(8)));
typedef float    f32x4 __attribute__((ext_vector_type(4)));
typedef float    f32x8 __attribute__((ext_vector_type(8)));

#define K1S 148   // layer1 k-steps of 32: 128 (x-part, 108 used) + 8*576
#define K2S 144   // layer2: 8 chunks * 576 / 32
#define OFF_W1P 0
#define OFF_W2P 4849664      // 4736*512*2
#define OFF_H   9568256      // + 4608*512*2
#define OFF_H1  11665408     // + 1024*512*4
#define OFF_CNT 13762560     // + 1024*512*4

// 9 features of scalar z: f[0]=silu(z); f[1+g]=B_g(z), g=0..7 (cubic B-spline,
// knots t_m = m*0.4 - 1, m=-3..8; support [-2.2, 2.2)).
__device__ __forceinline__ void feat9(float z, float f9[9]) {
  float s  = z / (1.f + __expf(-z));
  float q  = (z + 1.f) * 2.5f;
  float mf = floorf(q);
  float u  = q - mf;
  int   mi = (int)mf;
  if (!(mf >= -3.f && mf <= 7.f)) mi = 100;   // outside support -> all zero
  float u2 = u*u, u3 = u2*u, omu = 1.f - u;
  float p0 = omu*omu*omu * (1.f/6.f);
  float p1 = (3.f*u3 - 6.f*u2 + 4.f) * (1.f/6.f);
  float p2 = (-3.f*u3 + 3.f*u2 + 3.f*u + 1.f) * (1.f/6.f);
  float p3 = u3 * (1.f/6.f);
  f9[0] = s;
#pragma unroll
  for (int g = 0; g < 8; ++g) {
    int d = g - mi;            // 0..3 selects which of the 4 live polys
    float v = 0.f;
    v = (d==0) ? p0 : v; v = (d==1) ? p1 : v;
    v = (d==2) ? p2 : v; v = (d==3) ? p3 : v;
    f9[1+g] = v;
  }
}

// Pack weights fp32 -> fp16 in fragment-linear order:
// element index = ((nt*KS + ks)*64 + lane)*8 + e  holds W[k][n] with
// k = ks*32 + (lane>>4)*8 + e, n = nt*16 + (lane&15)   (MFMA B-frag layout).
// k-order layer1: k<128: x-part k=f*12+i (k>=108 zero pad);
//                 k>=128: kh=k-128: chunk c=kh/576, f=(kh%576)/64, sc=kh%64,
//                 i' = c*64+sc (h index), f=0 base_w else spline_w[.,.,f-1].
__global__ void __launch_bounds__(256)
pack_w(const float* __restrict__ bw1, const float* __restrict__ sw1,
       const float* __restrict__ bw2, const float* __restrict__ sw2,
       f16* __restrict__ w1p, f16* __restrict__ w2p)
{
  long idx = (long)blockIdx.x * 256 + threadIdx.x;
  const long N1 = 2424832L;               // 4736*512
  if (idx < N1) {
    int e = (int)(idx & 7); long q = idx >> 3;
    int l = (int)(q & 63);  q >>= 6;
    int ks = (int)(q % K1S); int nt = (int)(q / K1S);
    int k = ks*32 + (l>>4)*8 + e;
    int n = nt*16 + (l & 15);
    float v = 0.f;
    if (k < 108) {
      int f = k / 12, i = k - f*12;
      v = (f == 0) ? bw1[n*524 + i] : sw1[((n*524 + i) << 3) + f - 1];
    } else if (k >= 128) {
      int kh = k - 128; int c = kh / 576; int w_ = kh - c*576;
      int f = w_ >> 6, sc = w_ & 63; int i = 12 + c*64 + sc;
      v = (f == 0) ? bw1[n*524 + i] : sw1[((n*524 + i) << 3) + f - 1];
    }
    w1p[idx] = (f16)v;
  } else {
    idx -= N1;                            // 0 .. 4608*512
    int e = (int)(idx & 7); long q = idx >> 3;
    int l = (int)(q & 63);  q >>= 6;
    int ks = (int)(q % K2S); int nt = (int)(q / K2S);
    int k = ks*32 + (l>>4)*8 + e;
    int n = nt*16 + (l & 15);
    int c = k / 576; int w_ = k - c*576;
    int f = w_ >> 6, sc = w_ & 63; int i = c*64 + sc;
    float v = (f == 0) ? bw2[n*512 + i] : sw2[((n*512 + i) << 3) + f - 1];
    w2p[idx] = (f16)v;
  }
}

__device__ __forceinline__ void grp_barrier(unsigned* cnt, unsigned target) {
  __threadfence();                         // agent-visible my stores
  __syncthreads();
  if (threadIdx.x == 0) {
    __hip_atomic_fetch_add(cnt, 1u, __ATOMIC_RELEASE, __HIP_MEMORY_SCOPE_AGENT);
    unsigned v;
    do {
      v = __hip_atomic_load(cnt, __ATOMIC_ACQUIRE, __HIP_MEMORY_SCOPE_AGENT);
      if (v < target) __builtin_amdgcn_s_sleep(4);
    } while (v < target);
  }
  __syncthreads();
}

__global__ void __launch_bounds__(256)
kan_rnn(const float* __restrict__ xseq, const f16* __restrict__ w1p,
        const f16* __restrict__ w2p, float* __restrict__ hbuf,
        float* __restrict__ h1buf, unsigned* __restrict__ counters)
{
  // LDS: feature chunk [32 rows][576 k] fp16 (XOR-swizzled) + x-part [32][128]
  __shared__ __align__(16) unsigned char feat [32 * 1152];   // 36 KB
  __shared__ __align__(16) unsigned char xfeat[32 * 256];    // 8 KB

  const int tid = threadIdx.x, bid = blockIdx.x;
  const int slice = bid & 7, grp = bid >> 3, r0 = grp * 32;
  const int wv = tid >> 6, l = tid & 63;
  const int mt = wv & 1, ntp = wv >> 1;         // Mtile, Ntile-pair
  const int lLo = l & 15, lHi16 = (l >> 4) * 16;
  // feature-build role: thread -> (row rB, 8 scalars at ibB*8)
  const int rB = tid >> 3, ibB = tid & 7;
  const int swB = (rB & 7) << 4, rbaseB = rB * 1152;
  // A-fragment role
  const int ar = mt*16 + lLo;
  const int asw = (ar & 7) << 4;
  const int abase = ar * 1152, axbase = ar * 256;
  const int n0 = slice*4 + ntp*2;               // global 16-col tile index
  unsigned* cnt = counters + grp;

  // zero x-feature pad (k = 108..127, all rows) once
  for (int idx = tid; idx < 32*20; idx += 256) {
    int r = idx / 20, k = 108 + (idx % 20);
    *(f16*)(xfeat + r*256 + ((k*2) ^ ((r & 7) << 4))) = (f16)0.f;
  }

  const float* srcRow1 = hbuf  + (size_t)(r0 + rB) * 512;
  const float* srcRow2 = h1buf + (size_t)(r0 + rB) * 512;
  const f16x8* W1 = (const f16x8*)w1p;
  const f16x8* W2 = (const f16x8*)w2p;
  const int bL1a = (n0*K1S)*64 + l, bL1b = ((n0+1)*K1S)*64 + l;
  const int bL2a = (n0*K2S)*64 + l, bL2b = ((n0+1)*K2S)*64 + l;

  unsigned target = 0;
  for (int t = 0; t < 1024; ++t) {
    // ================= layer 1 =================
    // x features (h-independent part of z = [x_t, h])
    for (int idx = tid; idx < 384; idx += 256) {
      int r = idx / 12, i = idx - r*12;
      float z = xseq[(size_t)(r0 + r)*12288 + t*12 + i];
      float f9[9]; feat9(z, f9);
#pragma unroll
      for (int f = 0; f < 9; ++f)
        *(f16*)(xfeat + r*256 + (((f*12 + i)*2) ^ ((r & 7) << 4))) = (f16)f9[f];
    }
    f32x4 acc0 = {0.f,0.f,0.f,0.f}, acc1 = {0.f,0.f,0.f,0.f};
    __syncthreads();
    // x-chunk MFMA (4 k-steps)
#pragma unroll
    for (int ks = 0; ks < 4; ++ks) {
      f16x8 a = *(const f16x8*)(xfeat + axbase + ((ks*64 + lHi16) ^ asw));
      f16x8 b0 = W1[bL1a + ks*64];
      f16x8 b1 = W1[bL1b + ks*64];
      acc0 = __builtin_amdgcn_mfma_f32_16x16x32_f16(a, b0, acc0, 0, 0, 0);
      acc1 = __builtin_amdgcn_mfma_f32_16x16x32_f16(a, b1, acc1, 0, 0, 0);
    }
    // 8 h-chunks of 64 scalars (K=576 each)
    for (int c = 0; c < 8; ++c) {
      __syncthreads();                       // previous chunk's readers done
      {
        f32x8 hv = *(const f32x8*)(srcRow1 + c*64 + ibB*8);
        f16 o[9][8];
#pragma unroll
        for (int j = 0; j < 8; ++j) {
          float f9[9]; feat9(hv[j], f9);
#pragma unroll
          for (int f = 0; f < 9; ++f) o[f][j] = (f16)f9[f];
        }
#pragma unroll
        for (int f = 0; f < 9; ++f) {
          f16x8 v;
#pragma unroll
          for (int e = 0; e < 8; ++e) v[e] = o[f][e];
          *(f16x8*)(feat + rbaseB + ((f*128 + ibB*16) ^ swB)) = v;
        }
      }
      __syncthreads();                       // chunk built
      const int ksg = 4 + c*18;
#pragma unroll
      for (int ks = 0; ks < 18; ++ks) {
        f16x8 a = *(const f16x8*)(feat + abase + ((ks*64 + lHi16) ^ asw));
        f16x8 b0 = W1[bL1a + (ksg + ks)*64];
        f16x8 b1 = W1[bL1b + (ksg + ks)*64];
        acc0 = __builtin_amdgcn_mfma_f32_16x16x32_f16(a, b0, acc0, 0, 0, 0);
        acc1 = __builtin_amdgcn_mfma_f32_16x16x32_f16(a, b1, acc1, 0, 0, 0);
      }
    }
    // store h1 slice (f32): D layout col=l&15, row=(l>>4)*4+reg
#pragma unroll
    for (int reg = 0; reg < 4; ++reg) {
      int gr = r0 + mt*16 + (l >> 4)*4 + reg;
      h1buf[(size_t)gr*512 + (n0*16     + lLo)] = acc0[reg];
      h1buf[(size_t)gr*512 + ((n0+1)*16 + lLo)] = acc1[reg];
    }
    target += 8; grp_barrier(cnt, target);

    // ================= layer 2 =================
    acc0 = (f32x4){0.f,0.f,0.f,0.f}; acc1 = (f32x4){0.f,0.f,0.f,0.f};
    for (int c = 0; c < 8; ++c) {
      __syncthreads();
      {
        f32x8 hv = *(const f32x8*)(srcRow2 + c*64 + ibB*8);
        f16 o[9][8];
#pragma unroll
        for (int j = 0; j < 8; ++j) {
          float f9[9]; feat9(hv[j], f9);
#pragma unroll
          for (int f = 0; f < 9; ++f) o[f][j] = (f16)f9[f];
        }
#pragma unroll
        for (int f = 0; f < 9; ++f) {
          f16x8 v;
#pragma unroll
          for (int e = 0; e < 8; ++e) v[e] = o[f][e];
          *(f16x8*)(feat + rbaseB + ((f*128 + ibB*16) ^ swB)) = v;
        }
      }
      __syncthreads();
      const int ksg = c*18;
#pragma unroll
      for (int ks = 0; ks < 18; ++ks) {
        f16x8 a = *(const f16x8*)(feat + abase + ((ks*64 + lHi16) ^ asw));
        f16x8 b0 = W2[bL2a + (ksg + ks)*64];
        f16x8 b1 = W2[bL2b + (ksg + ks)*64];
        acc0 = __builtin_amdgcn_mfma_f32_16x16x32_f16(a, b0, acc0, 0, 0, 0);
        acc1 = __builtin_amdgcn_mfma_f32_16x16x32_f16(a, b1, acc1, 0, 0, 0);
      }
    }
    // h_new = tanh(.) stored f32
#pragma unroll
    for (int reg = 0; reg < 4; ++reg) {
      int gr = r0 + mt*16 + (l >> 4)*4 + reg;
      float v0 = acc0[reg]; v0 = 1.f - 2.f / (__expf(2.f*v0) + 1.f);
      float v1 = acc1[reg]; v1 = 1.f - 2.f / (__expf(2.f*v1) + 1.f);
      hbuf[(size_t)gr*512 + (n0*16     + lLo)] = v0;
      hbuf[(size_t)gr*512 + ((n0+1)*16 + lLo)] = v1;
    }
    target += 8; grp_barrier(cnt, target);
  }
}

__global__ void __launch_bounds__(64)
out_k(const float* __restrict__ hbuf, const float* __restrict__ wout,
      const float* __restrict__ bout, float* __restrict__ out)
{
  int b = blockIdx.x, l = threadIdx.x;
  float s0 = 0.f, s1 = 0.f, s2 = 0.f;
  for (int j = l; j < 512; j += 64) {
    float hv = hbuf[(size_t)b*512 + j];
    s0 += hv * wout[j]; s1 += hv * wout[512 + j]; s2 += hv * wout[1024 + j];
  }
#pragma unroll
  for (int off = 32; off > 0; off >>= 1) {
    s0 += __shfl_down(s0, off);
    s1 += __shfl_down(s1, off);
    s2 += __shfl_down(s2, off);
  }
  if (l == 0) {
    out[b*3 + 0] = s0 + bout[0];
    out[b*3 + 1] = s1 + bout[1];
    out[b*3 + 2] = s2 + bout[2];
  }
}

extern "C" void kernel_launch(void* const* d_in, const int* in_sizes, int n_in,
                              void* d_out, int out_size, void* d_ws, size_t ws_size,
                              hipStream_t stream) {
  const float* xseq = (const float*)d_in[0];
  const float* bw1  = (const float*)d_in[1];
  const float* sw1  = (const float*)d_in[2];
  const float* bw2  = (const float*)d_in[3];
  const float* sw2  = (const float*)d_in[4];
  const float* wout = (const float*)d_in[5];
  const float* bout = (const float*)d_in[6];
  char* ws = (char*)d_ws;
  f16*      w1p  = (f16*)(ws + OFF_W1P);
  f16*      w2p  = (f16*)(ws + OFF_W2P);
  float*    hbuf = (float*)(ws + OFF_H);
  float*    h1b  = (float*)(ws + OFF_H1);
  unsigned* cnts = (unsigned*)(ws + OFF_CNT);

  hipMemsetAsync(hbuf, 0, 1024*512*4, stream);   // h0 = 0
  hipMemsetAsync(cnts, 0, 128, stream);          // barrier counters
  pack_w<<<18688, 256, 0, stream>>>(bw1, sw1, bw2, sw2, w1p, w2p);
  kan_rnn<<<256, 256, 0, stream>>>(xseq, w1p, w2p, hbuf, h1b, cnts);
  out_k<<<1024, 64, 0, stream>>>(hbuf, wout, bout, (float*)d_out);
}